// Round 4
// baseline (252.728 us; speedup 1.0000x reference)
//
#include <hip/hip_runtime.h>
#include <hip/hip_bf16.h>

#define NB 4
#define NN 2048
#define FIN 64
#define DOUT 128

typedef __hip_bfloat16 bf16;
typedef __attribute__((ext_vector_type(8))) short short8;
typedef __attribute__((ext_vector_type(4))) float f32x4;
typedef __attribute__((ext_vector_type(4))) int int4v;

static __device__ __forceinline__ float bf2f(bf16 v) { return __bfloat162float(v); }
static __device__ __forceinline__ bf16  f2bf(float v) { return __float2bfloat16(v); }
static __device__ __forceinline__ unsigned bfbits(float v) {
    bf16 h = __float2bfloat16(v);
    return (unsigned)*reinterpret_cast<unsigned short*>(&h);
}

// vT layout (R2, kept): [b][key/64][dim 0..127][key%64] (bf16), dense 128B rows.
#define VT_IDX(b, key, d) ((((size_t)(b)*32 + ((key) >> 6))*128 + (d))*64 + ((key) & 63))

// ---------------- Kernel 1: q1,k1 (bf16), vT (bf16), proj (fp32) ----------------
__global__ __launch_bounds__(256) void k_gemm1(
    const float* __restrict__ x,
    const float* __restrict__ q1w, const float* __restrict__ q1b,
    const float* __restrict__ k1w, const float* __restrict__ k1b,
    const float* __restrict__ v1w, const float* __restrict__ v1b,
    const float* __restrict__ pw,
    bf16* __restrict__ qA, bf16* __restrict__ kA, bf16* __restrict__ vT,
    float* __restrict__ proj)
{
    __shared__ float At[64][65];
    __shared__ float Wt[64][65];
    const int rb = blockIdx.x;
    const int cb = blockIdx.y;
    const int mat = cb >> 1;
    const int c0 = (cb & 1) * 64;
    const float* W    = (mat==0)? q1w : (mat==1)? k1w : (mat==2)? v1w : pw;
    const float* bias = (mat==0)? q1b : (mat==1)? k1b : (mat==2)? v1b : nullptr;
    const int t = threadIdx.x;
    const int row0 = rb * 64;
    for (int e = t; e < 64*64; e += 256) {
        int r = e >> 6, c = e & 63;
        At[r][c] = x[(size_t)(row0 + r)*FIN + c];
        Wt[r][c] = W[r*DOUT + c0 + c];
    }
    __syncthreads();
    const int ty = t >> 4, tx = t & 15;
    float acc[4][4] = {};
    #pragma unroll 8
    for (int k = 0; k < 64; ++k) {
        float av[4], bv[4];
        #pragma unroll
        for (int i = 0; i < 4; ++i) av[i] = At[ty*4+i][k];
        #pragma unroll
        for (int j = 0; j < 4; ++j) bv[j] = Wt[k][tx*4+j];
        #pragma unroll
        for (int i = 0; i < 4; ++i)
            #pragma unroll
            for (int j = 0; j < 4; ++j)
                acc[i][j] = fmaf(av[i], bv[j], acc[i][j]);
    }
    #pragma unroll
    for (int i = 0; i < 4; ++i) {
        int gr = row0 + ty*4 + i;
        #pragma unroll
        for (int j = 0; j < 4; ++j) {
            int gc = c0 + tx*4 + j;
            float v = acc[i][j] + (bias ? bias[gc] : 0.f);
            if (mat == 0)      qA[(size_t)gr*DOUT + gc] = f2bf(v);
            else if (mat == 1) kA[(size_t)gr*DOUT + gc] = f2bf(v);
            else if (mat == 2) {
                int b = gr >> 11, n = gr & 2047;
                vT[VT_IDX(b, n, gc)] = f2bf(v);
            } else proj[(size_t)gr*DOUT + gc] = v;
        }
    }
}

// ---------------- Kernel 3: q2,k2 (bf16), vT = h @ W (+bias) ----------------
__global__ __launch_bounds__(256) void k_gemm2(
    const bf16* __restrict__ h,
    const float* __restrict__ q2w, const float* __restrict__ q2b,
    const float* __restrict__ k2w, const float* __restrict__ k2b,
    const float* __restrict__ v2w, const float* __restrict__ v2b,
    bf16* __restrict__ qA, bf16* __restrict__ kA, bf16* __restrict__ vT)
{
    __shared__ float At[64][65];
    __shared__ float Wt[64][65];
    const int rb = blockIdx.x, cb = blockIdx.y;
    const int mat = cb >> 1, c0 = (cb & 1)*64;
    const float* W    = (mat==0)? q2w : (mat==1)? k2w : v2w;
    const float* bias = (mat==0)? q2b : (mat==1)? k2b : v2b;
    const int t = threadIdx.x, ty = t >> 4, tx = t & 15, row0 = rb*64;
    float acc[4][4] = {};
    for (int kc = 0; kc < 2; ++kc) {
        __syncthreads();
        for (int e = t; e < 64*64; e += 256) {
            int r = e >> 6, c = e & 63;
            At[r][c] = bf2f(h[(size_t)(row0+r)*DOUT + kc*64 + c]);
            Wt[r][c] = W[(kc*64+r)*DOUT + c0 + c];
        }
        __syncthreads();
        #pragma unroll 8
        for (int k = 0; k < 64; ++k) {
            float av[4], bv[4];
            #pragma unroll
            for (int i = 0; i < 4; ++i) av[i] = At[ty*4+i][k];
            #pragma unroll
            for (int j = 0; j < 4; ++j) bv[j] = Wt[k][tx*4+j];
            #pragma unroll
            for (int i = 0; i < 4; ++i)
                #pragma unroll
                for (int j = 0; j < 4; ++j)
                    acc[i][j] = fmaf(av[i], bv[j], acc[i][j]);
        }
    }
    #pragma unroll
    for (int i = 0; i < 4; ++i) {
        int gr = row0 + ty*4 + i;
        #pragma unroll
        for (int j = 0; j < 4; ++j) {
            int gc = c0 + tx*4 + j;
            float v = acc[i][j] + bias[gc];
            if (mat == 0)      qA[(size_t)gr*DOUT + gc] = f2bf(v);
            else if (mat == 1) kA[(size_t)gr*DOUT + gc] = f2bf(v);
            else {
                int b = gr >> 11, n = gr & 2047;
                vT[VT_IDX(b, n, gc)] = f2bf(v);
            }
        }
    }
}

// ---------------- MFMA flash attention v3: software-pipelined loads ----------------
// Theory (R2/R4): counters show MfmaUtil 5% / VALUBusy 26% / HBM 1% -> ~75% stall.
// Back-solve: ~1900 stall cycles/iter = MULTIPLE serialized cache round-trips.
// Cause: compiler allocated 44/56 VGPRs (occupancy heuristic) -> no registers to
// hold loads in flight -> each K/V tile is load->wait->use. Fix:
//   (a) __launch_bounds__(.., 4): cap occupancy at 4 waves/EU -> 128-VGPR budget.
//   (b) explicit issue-early/consume-late order: K tiles streamed 2-ahead in S^T;
//       all ks2=0 V loads issued before pack; ks2=1 V loads issued before PV0.
//   (c) unroll 2 on the iter loop (static indices, bounded code size — the R3
//       full unroll is suspected in the container failure).
// MODE 0: relu -> h bf16 (gat1, D=32, H=4). MODE 1: +proj residual + LayerNorm -> fp32.
template<int D, int MODE, int NW>
__global__ __launch_bounds__(NW*64, 4) void k_attn_mfma(
    const bf16* __restrict__ qA, const bf16* __restrict__ kA, const bf16* __restrict__ vT,
    const float* __restrict__ proj, const float* __restrict__ lng, const float* __restrict__ lnb,
    bf16* __restrict__ hout, float* __restrict__ fout)
{
    constexpr int NKS = D / 32;     // 32-dim k-steps in S^T
    constexpr int NMT = D / 16;     // 16-dim m-tiles of O^T
    constexpr int ITERS = NN / (64 * NW);

    __shared__ float lbuf[NW][16];
    constexpr int OSW = (MODE == 0) ? (D + 1) : (D + 2);
    __shared__ char oS_raw[(size_t)NW * 16 * OSW * ((MODE == 0) ? 4 : 2)];

    const float scale = (D == 32) ? 0.17677669529663687f : 0.08838834764831843f;

    // XCD-aware swizzle (kept from R1; harmless, helps L2 residency).
    const unsigned wg  = blockIdx.x + (unsigned)gridDim.x * blockIdx.y;
    const unsigned xcd = wg & 7u;
    const unsigned idx = wg >> 3;
    int qt, bh;
    if constexpr (MODE == 0) {
        bh = (int)((xcd << 1) | (idx >> 7));
        qt = (int)(idx & 127u);
    } else {
        bh = (int)(xcd >> 1);
        qt = (int)(((xcd & 1u) << 6) | idx);
    }

    const int b  = (MODE == 0) ? (bh >> 2) : bh;
    const int hd = (MODE == 0) ? (bh & 3) : 0;
    const int q0 = qt * 16;
    const int wave = threadIdx.x >> 6, lane = threadIdx.x & 63;
    const int n16 = lane & 15, q4 = lane >> 4;

    const short* qbase = (const short*)qA + ((size_t)b*NN)*DOUT + hd*32;
    const short* kbase = (const short*)kA + ((size_t)b*NN)*DOUT + hd*32;
    const short* vbase = (const short*)vT + (size_t)b*32*128*64 + (size_t)(hd*32)*64;

    // Q B-fragments — held in regs
    short8 qf[NKS];
    #pragma unroll
    for (int ks = 0; ks < NKS; ++ks)
        qf[ks] = *(const short8*)(qbase + (size_t)(q0 + n16)*DOUT + ks*32 + q4*8);

    f32x4 acc[NMT];
    #pragma unroll
    for (int mt = 0; mt < NMT; ++mt) acc[mt] = f32x4{0.f, 0.f, 0.f, 0.f};
    float l_lane = 0.f;

    // bpermute source lanes for the P gather (uniform per lane)
    const int srcA = n16 + ((q4 & 1) * 2) * 16;
    const int srcB = srcA + 16;
    const bool selhi = (q4 >= 2);

    #pragma unroll 2
    for (int kt0 = 0; kt0 < ITERS; ++kt0) {
        const int kt = wave * ITERS + kt0;     // this wave's key chunk (64 keys)
        const short* krow = kbase + (size_t)(kt*64)*DOUT;
        const short* vrow = vbase + (size_t)kt*128*64;

        // ---- S^T phase: stream K m-tiles with 2-tile lookahead
        short8 kf[4][NKS];
        #pragma unroll
        for (int mt = 0; mt < 2; ++mt)
            #pragma unroll
            for (int ks = 0; ks < NKS; ++ks)
                kf[mt][ks] = *(const short8*)(krow + (size_t)(mt*16 + n16)*DOUT + ks*32 + q4*8);

        f32x4 sc[4];
        #pragma unroll
        for (int mt = 0; mt < 4; ++mt) {
            if (mt + 2 < 4) {
                #pragma unroll
                for (int ks = 0; ks < NKS; ++ks)
                    kf[mt+2][ks] = *(const short8*)(krow + (size_t)((mt+2)*16 + n16)*DOUT + ks*32 + q4*8);
            }
            f32x4 c = f32x4{0.f, 0.f, 0.f, 0.f};
            #pragma unroll
            for (int ks = 0; ks < NKS; ++ks)
                c = __builtin_amdgcn_mfma_f32_16x16x32_bf16(kf[mt][ks], qf[ks], c, 0, 0, 0);
            // exp (no-max), accumulate denominator (lane-local for query n16);
            // VALU here also covers the in-flight K prefetch latency.
            #pragma unroll
            for (int r = 0; r < 4; ++r) {
                float p = __expf(c[r] * scale);
                c[r] = p;
                l_lane += p;
            }
            sc[mt] = c;
        }

        // ---- issue ks2=0 V loads NOW; pack phase (pure VALU) hides their latency
        short8 vv0[NMT];
        #pragma unroll
        for (int mt = 0; mt < NMT; ++mt)
            vv0[mt] = *(const short8*)(vrow + (size_t)(mt*16 + n16)*64 + 0*32 + q4*8);

        // ---- pack P^T tiles to bf16 pairs: w0=keys(reg0,1), w1=keys(reg2,3)
        unsigned w0v[4], w1v[4];
        #pragma unroll
        for (int mt = 0; mt < 4; ++mt) {
            w0v[mt] = bfbits(sc[mt][0]) | (bfbits(sc[mt][1]) << 16);
            w1v[mt] = bfbits(sc[mt][2]) | (bfbits(sc[mt][3]) << 16);
        }

        // ---- gather P fragment for ks2=0 (bpermute), then issue ks2=1 V loads
        int4v pw0;
        { unsigned a = __shfl(w0v[0], srcA), bx = __shfl(w0v[1], srcA);
          pw0.x = selhi ? (int)bx : (int)a; }
        { unsigned a = __shfl(w1v[0], srcA), bx = __shfl(w1v[1], srcA);
          pw0.y = selhi ? (int)bx : (int)a; }
        { unsigned a = __shfl(w0v[0], srcB), bx = __shfl(w0v[1], srcB);
          pw0.z = selhi ? (int)bx : (int)a; }
        { unsigned a = __shfl(w1v[0], srcB), bx = __shfl(w1v[1], srcB);
          pw0.w = selhi ? (int)bx : (int)a; }
        short8 pf0 = __builtin_bit_cast(short8, pw0);

        short8 vv1[NMT];
        #pragma unroll
        for (int mt = 0; mt < NMT; ++mt)
            vv1[mt] = *(const short8*)(vrow + (size_t)(mt*16 + n16)*64 + 1*32 + q4*8);

        // ---- PV ks2=0 (vv0 loads have had pack+gather distance)
        #pragma unroll
        for (int mt = 0; mt < NMT; ++mt)
            acc[mt] = __builtin_amdgcn_mfma_f32_16x16x32_bf16(vv0[mt], pf0, acc[mt], 0, 0, 0);

        // ---- gather P fragment for ks2=1, PV ks2=1
        int4v pw1;
        { unsigned a = __shfl(w0v[2], srcA), bx = __shfl(w0v[3], srcA);
          pw1.x = selhi ? (int)bx : (int)a; }
        { unsigned a = __shfl(w1v[2], srcA), bx = __shfl(w1v[3], srcA);
          pw1.y = selhi ? (int)bx : (int)a; }
        { unsigned a = __shfl(w0v[2], srcB), bx = __shfl(w0v[3], srcB);
          pw1.z = selhi ? (int)bx : (int)a; }
        { unsigned a = __shfl(w1v[2], srcB), bx = __shfl(w1v[3], srcB);
          pw1.w = selhi ? (int)bx : (int)a; }
        short8 pf1 = __builtin_bit_cast(short8, pw1);

        #pragma unroll
        for (int mt = 0; mt < NMT; ++mt)
            acc[mt] = __builtin_amdgcn_mfma_f32_16x16x32_bf16(vv1[mt], pf1, acc[mt], 0, 0, 0);
    }

    // ---- finalize denominator for query n16: reduce across q4 groups
    l_lane += __shfl_xor(l_lane, 16);
    l_lane += __shfl_xor(l_lane, 32);
    if (q4 == 0) lbuf[wave][n16] = l_lane;

    // ---- publish O^T partials
    if (MODE == 0) {
        float (&oSf)[NW][16][D + 1] = *reinterpret_cast<float (*)[NW][16][D + 1]>(oS_raw);
        #pragma unroll
        for (int mt = 0; mt < NMT; ++mt)
            #pragma unroll
            for (int r = 0; r < 4; ++r)
                oSf[wave][n16][mt*16 + q4*4 + r] = acc[mt][r];
    } else {
        unsigned short (&oSh)[NW][16][D + 2] =
            *reinterpret_cast<unsigned short (*)[NW][16][D + 2]>(oS_raw);
        #pragma unroll
        for (int mt = 0; mt < NMT; ++mt)
            #pragma unroll
            for (int r = 0; r < 4; ++r)
                oSh[wave][n16][mt*16 + q4*4 + r] = (unsigned short)bfbits(acc[mt][r]);
    }
    __syncthreads();  // single barrier: merge reads all splits

    if (MODE == 0) {
        float (&oSf)[NW][16][D + 1] = *reinterpret_cast<float (*)[NW][16][D + 1]>(oS_raw);
        const int q = wave*4 + (lane >> 4);
        const int d2 = (lane & 15)*2;
        float denom = 0.f, o0 = 0.f, o1 = 0.f;
        #pragma unroll
        for (int s = 0; s < NW; ++s) {
            denom += lbuf[s][q];
            o0 += oSf[s][q][d2];
            o1 += oSf[s][q][d2 + 1];
        }
        float di = 1.f / denom;
        unsigned w = bfbits(fmaxf(o0*di, 0.f)) | (bfbits(fmaxf(o1*di, 0.f)) << 16);
        *(unsigned*)&hout[((size_t)b*NN + q0 + q)*DOUT + hd*32 + d2] = w;
    } else {
        unsigned short (&oSh)[NW][16][D + 2] =
            *reinterpret_cast<unsigned short (*)[NW][16][D + 2]>(oS_raw);
        const int q = wave*2 + (lane >> 5);
        const int il = lane & 31;
        float denom = 0.f;
        #pragma unroll
        for (int s = 0; s < NW; ++s) denom += lbuf[s][q];
        float di = 1.f / denom;
        size_t base = ((size_t)b*NN + q0 + q)*DOUT + il*4;
        float4 pr = *(const float4*)(proj + base);
        float y[4];
        #pragma unroll
        for (int c = 0; c < 4; ++c) {
            float o = 0.f;
            #pragma unroll
            for (int s = 0; s < NW; ++s)
                o += __uint_as_float(((unsigned)oSh[s][q][il*4 + c]) << 16);
            y[c] = o*di + ((const float*)&pr)[c];
        }
        float ssum = y[0] + y[1] + y[2] + y[3];
        #pragma unroll
        for (int off = 16; off >= 1; off >>= 1) ssum += __shfl_xor(ssum, off);
        float mu = ssum * (1.f/128.f);
        float vs = 0.f;
        #pragma unroll
        for (int c = 0; c < 4; ++c) { float d = y[c] - mu; vs += d*d; }
        #pragma unroll
        for (int off = 16; off >= 1; off >>= 1) vs += __shfl_xor(vs, off);
        float rs = rsqrtf(vs * (1.f/128.f) + 1e-3f);
        float4 g4 = *(const float4*)(lng + il*4);
        float4 b4 = *(const float4*)(lnb + il*4);
        float4 o4;
        #pragma unroll
        for (int c = 0; c < 4; ++c) {
            float o = (y[c] - mu)*rs*((const float*)&g4)[c] + ((const float*)&b4)[c];
            if (!(o == o)) o = 12345.0f;  // NaN sentinel (never hit on a passing run)
            ((float*)&o4)[c] = o;
        }
        *(float4*)(fout + base) = o4;
    }
}

extern "C" void kernel_launch(void* const* d_in, const int* in_sizes, int n_in,
                              void* d_out, int out_size, void* d_ws, size_t ws_size,
                              hipStream_t stream)
{
    const float* x   = (const float*)d_in[0];
    // d_in[1] = emb is dead: adj = sigmoid(l2norm(emb)@l2norm(emb)^T) in [0.27,1],
    // diag forced 1 -> adj==0 never true -> dense attention.
    const float* q1w = (const float*)d_in[2];
    const float* q1b = (const float*)d_in[3];
    const float* k1w = (const float*)d_in[4];
    const float* k1b = (const float*)d_in[5];
    const float* v1w = (const float*)d_in[6];
    const float* v1b = (const float*)d_in[7];
    const float* q2w = (const float*)d_in[8];
    const float* q2b = (const float*)d_in[9];
    const float* k2w = (const float*)d_in[10];
    const float* k2b = (const float*)d_in[11];
    const float* v2w = (const float*)d_in[12];
    const float* v2b = (const float*)d_in[13];
    const float* pw  = (const float*)d_in[14];
    const float* lng = (const float*)d_in[15];
    const float* lnb = (const float*)d_in[16];

    // Workspace: 12 MB (proven). q/k/vT slots reused across the two layers.
    const size_t SZ = (size_t)NB*NN*DOUT;           // 1,048,576 elements
    char* wsb = (char*)d_ws;
    bf16*  qA   = (bf16*)(wsb + 0*SZ*2);            // 2 MB
    bf16*  kA   = (bf16*)(wsb + 1*SZ*2);            // 2 MB
    bf16*  vT   = (bf16*)(wsb + 2*SZ*2);            // 2 MB  [b][key/64][128][64]
    float* proj = (float*)(wsb + 3*SZ*2);           // 4 MB
    bf16*  h    = (bf16*)(wsb + 3*SZ*2 + SZ*4);     // 2 MB

    k_gemm1<<<dim3(128, 8), 256, 0, stream>>>(x, q1w, q1b, k1w, k1b, v1w, v1b, pw,
                                              qA, kA, vT, proj);
    k_attn_mfma<32, 0, 4><<<dim3(128, 16), 256, 0, stream>>>(
        qA, kA, vT, nullptr, nullptr, nullptr, h, nullptr);
    k_gemm2<<<dim3(128, 6), 256, 0, stream>>>(h, q2w, q2b, k2w, k2b, v2w, v2b,
                                              qA, kA, vT);
    k_attn_mfma<128, 1, 8><<<dim3(128, 4), 512, 0, stream>>>(
        qA, kA, vT, proj, lng, lnb, nullptr, (float*)d_out);
}

// Round 5
// 196.131 us; speedup vs baseline: 1.2886x; 1.2886x over previous
//
#include <hip/hip_runtime.h>
#include <hip/hip_bf16.h>

#define NB 4
#define NN 2048
#define FIN 64
#define DOUT 128

typedef __hip_bfloat16 bf16;
typedef __attribute__((ext_vector_type(8))) short short8;
typedef __attribute__((ext_vector_type(4))) float f32x4;
typedef __attribute__((ext_vector_type(4))) int int4v;

static __device__ __forceinline__ float bf2f(bf16 v) { return __bfloat162float(v); }
static __device__ __forceinline__ bf16  f2bf(float v) { return __float2bfloat16(v); }
static __device__ __forceinline__ unsigned bfbits(float v) {
    bf16 h = __float2bfloat16(v);
    return (unsigned)*reinterpret_cast<unsigned short*>(&h);
}

// vT layout (R2, kept): [b][key/64][dim 0..127][key%64] (bf16), dense 128B rows.
#define VT_IDX(b, key, d) ((((size_t)(b)*32 + ((key) >> 6))*128 + (d))*64 + ((key) & 63))

// ---------------- Kernel 1: q1,k1 (bf16), vT (bf16), proj (fp32) ----------------
__global__ __launch_bounds__(256) void k_gemm1(
    const float* __restrict__ x,
    const float* __restrict__ q1w, const float* __restrict__ q1b,
    const float* __restrict__ k1w, const float* __restrict__ k1b,
    const float* __restrict__ v1w, const float* __restrict__ v1b,
    const float* __restrict__ pw,
    bf16* __restrict__ qA, bf16* __restrict__ kA, bf16* __restrict__ vT,
    float* __restrict__ proj)
{
    __shared__ float At[64][65];
    __shared__ float Wt[64][65];
    const int rb = blockIdx.x;
    const int cb = blockIdx.y;
    const int mat = cb >> 1;
    const int c0 = (cb & 1) * 64;
    const float* W    = (mat==0)? q1w : (mat==1)? k1w : (mat==2)? v1w : pw;
    const float* bias = (mat==0)? q1b : (mat==1)? k1b : (mat==2)? v1b : nullptr;
    const int t = threadIdx.x;
    const int row0 = rb * 64;
    for (int e = t; e < 64*64; e += 256) {
        int r = e >> 6, c = e & 63;
        At[r][c] = x[(size_t)(row0 + r)*FIN + c];
        Wt[r][c] = W[r*DOUT + c0 + c];
    }
    __syncthreads();
    const int ty = t >> 4, tx = t & 15;
    float acc[4][4] = {};
    #pragma unroll 8
    for (int k = 0; k < 64; ++k) {
        float av[4], bv[4];
        #pragma unroll
        for (int i = 0; i < 4; ++i) av[i] = At[ty*4+i][k];
        #pragma unroll
        for (int j = 0; j < 4; ++j) bv[j] = Wt[k][tx*4+j];
        #pragma unroll
        for (int i = 0; i < 4; ++i)
            #pragma unroll
            for (int j = 0; j < 4; ++j)
                acc[i][j] = fmaf(av[i], bv[j], acc[i][j]);
    }
    #pragma unroll
    for (int i = 0; i < 4; ++i) {
        int gr = row0 + ty*4 + i;
        #pragma unroll
        for (int j = 0; j < 4; ++j) {
            int gc = c0 + tx*4 + j;
            float v = acc[i][j] + (bias ? bias[gc] : 0.f);
            if (mat == 0)      qA[(size_t)gr*DOUT + gc] = f2bf(v);
            else if (mat == 1) kA[(size_t)gr*DOUT + gc] = f2bf(v);
            else if (mat == 2) {
                int b = gr >> 11, n = gr & 2047;
                vT[VT_IDX(b, n, gc)] = f2bf(v);
            } else proj[(size_t)gr*DOUT + gc] = v;
        }
    }
}

// ---------------- Kernel 3: q2,k2 (bf16), vT = h @ W (+bias) ----------------
__global__ __launch_bounds__(256) void k_gemm2(
    const bf16* __restrict__ h,
    const float* __restrict__ q2w, const float* __restrict__ q2b,
    const float* __restrict__ k2w, const float* __restrict__ k2b,
    const float* __restrict__ v2w, const float* __restrict__ v2b,
    bf16* __restrict__ qA, bf16* __restrict__ kA, bf16* __restrict__ vT)
{
    __shared__ float At[64][65];
    __shared__ float Wt[64][65];
    const int rb = blockIdx.x, cb = blockIdx.y;
    const int mat = cb >> 1, c0 = (cb & 1)*64;
    const float* W    = (mat==0)? q2w : (mat==1)? k2w : v2w;
    const float* bias = (mat==0)? q2b : (mat==1)? k2b : v2b;
    const int t = threadIdx.x, ty = t >> 4, tx = t & 15, row0 = rb*64;
    float acc[4][4] = {};
    for (int kc = 0; kc < 2; ++kc) {
        __syncthreads();
        for (int e = t; e < 64*64; e += 256) {
            int r = e >> 6, c = e & 63;
            At[r][c] = bf2f(h[(size_t)(row0+r)*DOUT + kc*64 + c]);
            Wt[r][c] = W[(kc*64+r)*DOUT + c0 + c];
        }
        __syncthreads();
        #pragma unroll 8
        for (int k = 0; k < 64; ++k) {
            float av[4], bv[4];
            #pragma unroll
            for (int i = 0; i < 4; ++i) av[i] = At[ty*4+i][k];
            #pragma unroll
            for (int j = 0; j < 4; ++j) bv[j] = Wt[k][tx*4+j];
            #pragma unroll
            for (int i = 0; i < 4; ++i)
                #pragma unroll
                for (int j = 0; j < 4; ++j)
                    acc[i][j] = fmaf(av[i], bv[j], acc[i][j]);
        }
    }
    #pragma unroll
    for (int i = 0; i < 4; ++i) {
        int gr = row0 + ty*4 + i;
        #pragma unroll
        for (int j = 0; j < 4; ++j) {
            int gc = c0 + tx*4 + j;
            float v = acc[i][j] + bias[gc];
            if (mat == 0)      qA[(size_t)gr*DOUT + gc] = f2bf(v);
            else if (mat == 1) kA[(size_t)gr*DOUT + gc] = f2bf(v);
            else {
                int b = gr >> 11, n = gr & 2047;
                vT[VT_IDX(b, n, gc)] = f2bf(v);
            }
        }
    }
}

// ---------------- MFMA flash attention v5: NQ query-tiles per block ----------------
// R5 theory: the invariant across r0-r4 is "512MB of scattered 64B cache requests
// = 65us" with ALL pipes <10% busy -> request-rate/queueing wall, not BW, not
// latency-chain, not registers (r4: compiler spilled rather than pipeline, WRITE
// 43MB). The only lever under a queueing model: FEWER requests. NQ=2 q-tiles per
// block reuse every K/V fragment load for 2 MFMAs -> K/V traffic halves (512->256MB).
// Loop body is the r0 straight-line form (no lookahead arrays -> no spill).
// MODE 0: relu -> h bf16 (gat1, D=32, H=4). MODE 1: +proj residual + LayerNorm -> fp32.
template<int D, int MODE, int NW, int NQ>
__global__ __launch_bounds__(NW*64, 2) void k_attn_mfma(
    const bf16* __restrict__ qA, const bf16* __restrict__ kA, const bf16* __restrict__ vT,
    const float* __restrict__ proj, const float* __restrict__ lng, const float* __restrict__ lnb,
    bf16* __restrict__ hout, float* __restrict__ fout)
{
    constexpr int NKS = D / 32;     // 32-dim k-steps in S^T
    constexpr int NMT = D / 16;     // 16-dim m-tiles of O^T
    constexpr int ITERS = NN / (64 * NW);

    __shared__ float lbuf[NW][NQ*16];
    constexpr int OSW = (MODE == 0) ? (D + 1) : (D + 2);
    __shared__ char oS_raw[(size_t)NW * NQ*16 * OSW * ((MODE == 0) ? 4 : 2)];

    const float scale = (D == 32) ? 0.17677669529663687f : 0.08838834764831843f;

    // XCD-aware swizzle (xcd = linear_wg % 8). MODE0: 1024 wgs -> 2 head-pairs/XCD.
    // MODE1: 256 wgs -> 1 batch per XCD-pair.
    const unsigned wg  = blockIdx.x + (unsigned)gridDim.x * blockIdx.y;
    const unsigned xcd = wg & 7u;
    const unsigned idx = wg >> 3;
    int qb, bh;
    if constexpr (MODE == 0) {
        bh = (int)((xcd << 1) | (idx >> 6));   // 0..15, idx 0..127
        qb = (int)(idx & 63u);                 // 0..63 q-blocks
    } else {
        bh = (int)(xcd >> 1);                  // 0..3, idx 0..31
        qb = (int)(((xcd & 1u) << 5) | idx);   // 0..63 q-blocks
    }

    const int b  = (MODE == 0) ? (bh >> 2) : bh;
    const int hd = (MODE == 0) ? (bh & 3) : 0;
    const int q0 = qb * (16*NQ);
    const int wave = threadIdx.x >> 6, lane = threadIdx.x & 63;
    const int n16 = lane & 15, q4 = lane >> 4;

    const short* qbase = (const short*)qA + ((size_t)b*NN)*DOUT + hd*32;
    const short* kbase = (const short*)kA + ((size_t)b*NN)*DOUT + hd*32;
    const short* vbase = (const short*)vT + (size_t)b*32*128*64 + (size_t)(hd*32)*64;

    // Q B-fragments for each of the NQ query tiles — held in regs
    short8 qf[NQ][NKS];
    #pragma unroll
    for (int qq = 0; qq < NQ; ++qq)
        #pragma unroll
        for (int ks = 0; ks < NKS; ++ks)
            qf[qq][ks] = *(const short8*)(qbase + (size_t)(q0 + qq*16 + n16)*DOUT + ks*32 + q4*8);

    f32x4 acc[NQ][NMT];
    #pragma unroll
    for (int qq = 0; qq < NQ; ++qq)
        #pragma unroll
        for (int mt = 0; mt < NMT; ++mt) acc[qq][mt] = f32x4{0.f, 0.f, 0.f, 0.f};
    float l_lane[NQ];
    #pragma unroll
    for (int qq = 0; qq < NQ; ++qq) l_lane[qq] = 0.f;

    // bpermute source lanes for the P gather (uniform per lane)
    const int srcA = n16 + ((q4 & 1) * 2) * 16;
    const int srcB = srcA + 16;
    const bool selhi = (q4 >= 2);

    for (int kt0 = 0; kt0 < ITERS; ++kt0) {
        const int kt = wave * ITERS + kt0;     // this wave's key chunk (64 keys)
        const short* krow = kbase + (size_t)(kt*64)*DOUT;
        const short* vrow = vbase + (size_t)kt*128*64;

        // ---- S^T: 4 m-tiles of 16 keys; each K fragment feeds NQ MFMAs.
        unsigned w0v[NQ][4], w1v[NQ][4];
        #pragma unroll
        for (int mt = 0; mt < 4; ++mt) {
            f32x4 c[NQ];
            #pragma unroll
            for (int qq = 0; qq < NQ; ++qq) c[qq] = f32x4{0.f, 0.f, 0.f, 0.f};
            #pragma unroll
            for (int ks = 0; ks < NKS; ++ks) {
                short8 kf = *(const short8*)(krow + (size_t)(mt*16 + n16)*DOUT + ks*32 + q4*8);
                #pragma unroll
                for (int qq = 0; qq < NQ; ++qq)
                    c[qq] = __builtin_amdgcn_mfma_f32_16x16x32_bf16(kf, qf[qq][ks], c[qq], 0, 0, 0);
            }
            // exp (no-max), accumulate denominator, pack immediately (short live range)
            #pragma unroll
            for (int qq = 0; qq < NQ; ++qq) {
                #pragma unroll
                for (int r = 0; r < 4; ++r) {
                    float p = __expf(c[qq][r] * scale);
                    c[qq][r] = p;
                    l_lane[qq] += p;
                }
                w0v[qq][mt] = bfbits(c[qq][0]) | (bfbits(c[qq][1]) << 16);
                w1v[qq][mt] = bfbits(c[qq][2]) | (bfbits(c[qq][3]) << 16);
            }
        }

        // ---- PV: 2 k-steps of 32 keys; each V fragment feeds NQ MFMAs.
        #pragma unroll
        for (int ks2 = 0; ks2 < 2; ++ks2) {
            const int t0 = ks2*2, t1 = ks2*2 + 1;
            short8 pf[NQ];
            #pragma unroll
            for (int qq = 0; qq < NQ; ++qq) {
                int4v pw;
                { unsigned a = __shfl(w0v[qq][t0], srcA), bx = __shfl(w0v[qq][t1], srcA);
                  pw.x = selhi ? (int)bx : (int)a; }
                { unsigned a = __shfl(w1v[qq][t0], srcA), bx = __shfl(w1v[qq][t1], srcA);
                  pw.y = selhi ? (int)bx : (int)a; }
                { unsigned a = __shfl(w0v[qq][t0], srcB), bx = __shfl(w0v[qq][t1], srcB);
                  pw.z = selhi ? (int)bx : (int)a; }
                { unsigned a = __shfl(w1v[qq][t0], srcB), bx = __shfl(w1v[qq][t1], srcB);
                  pw.w = selhi ? (int)bx : (int)a; }
                pf[qq] = __builtin_bit_cast(short8, pw);
            }
            #pragma unroll
            for (int mt = 0; mt < NMT; ++mt) {
                short8 vf = *(const short8*)(vrow + (size_t)(mt*16 + n16)*64 + ks2*32 + q4*8);
                #pragma unroll
                for (int qq = 0; qq < NQ; ++qq)
                    acc[qq][mt] = __builtin_amdgcn_mfma_f32_16x16x32_bf16(vf, pf[qq], acc[qq][mt], 0, 0, 0);
            }
        }
    }

    // ---- finalize denominators: reduce across q4 groups
    #pragma unroll
    for (int qq = 0; qq < NQ; ++qq) {
        l_lane[qq] += __shfl_xor(l_lane[qq], 16);
        l_lane[qq] += __shfl_xor(l_lane[qq], 32);
        if (q4 == 0) lbuf[wave][qq*16 + n16] = l_lane[qq];
    }

    // ---- publish O^T partials
    if (MODE == 0) {
        float (&oSf)[NW][NQ*16][D + 1] = *reinterpret_cast<float (*)[NW][NQ*16][D + 1]>(oS_raw);
        #pragma unroll
        for (int qq = 0; qq < NQ; ++qq)
            #pragma unroll
            for (int mt = 0; mt < NMT; ++mt)
                #pragma unroll
                for (int r = 0; r < 4; ++r)
                    oSf[wave][qq*16 + n16][mt*16 + q4*4 + r] = acc[qq][mt][r];
    } else {
        unsigned short (&oSh)[NW][NQ*16][D + 2] =
            *reinterpret_cast<unsigned short (*)[NW][NQ*16][D + 2]>(oS_raw);
        #pragma unroll
        for (int qq = 0; qq < NQ; ++qq)
            #pragma unroll
            for (int mt = 0; mt < NMT; ++mt)
                #pragma unroll
                for (int r = 0; r < 4; ++r)
                    oSh[wave][qq*16 + n16][mt*16 + q4*4 + r] = (unsigned short)bfbits(acc[qq][mt][r]);
    }
    __syncthreads();  // single barrier: merge reads all splits

    if (MODE == 0) {
        // merge + ReLU per q-tile: lane handles query wave*4+(lane>>4), dims (lane&15)*2..+1
        float (&oSf)[NW][NQ*16][D + 1] = *reinterpret_cast<float (*)[NW][NQ*16][D + 1]>(oS_raw);
        const int ql = wave*4 + (lane >> 4);
        const int d2 = (lane & 15)*2;
        #pragma unroll
        for (int qq = 0; qq < NQ; ++qq) {
            const int row = qq*16 + ql;
            float denom = 0.f, o0 = 0.f, o1 = 0.f;
            #pragma unroll
            for (int s = 0; s < NW; ++s) {
                denom += lbuf[s][row];
                o0 += oSf[s][row][d2];
                o1 += oSf[s][row][d2 + 1];
            }
            float di = 1.f / denom;
            unsigned w = bfbits(fmaxf(o0*di, 0.f)) | (bfbits(fmaxf(o1*di, 0.f)) << 16);
            *(unsigned*)&hout[((size_t)b*NN + q0 + row)*DOUT + hd*32 + d2] = w;
        }
    } else {
        // merge + residual + LayerNorm per q-tile: lane handles query wave*2+(lane>>5),
        // dims (lane&31)*4..+3; row reduction via shfl_xor 16..1.
        unsigned short (&oSh)[NW][NQ*16][D + 2] =
            *reinterpret_cast<unsigned short (*)[NW][NQ*16][D + 2]>(oS_raw);
        const int ql = wave*2 + (lane >> 5);
        const int il = lane & 31;
        #pragma unroll
        for (int qq = 0; qq < NQ; ++qq) {
            const int row = qq*16 + ql;
            float denom = 0.f;
            #pragma unroll
            for (int s = 0; s < NW; ++s) denom += lbuf[s][row];
            float di = 1.f / denom;
            size_t base = ((size_t)b*NN + q0 + row)*DOUT + il*4;
            float4 pr = *(const float4*)(proj + base);
            float y[4];
            #pragma unroll
            for (int c = 0; c < 4; ++c) {
                float o = 0.f;
                #pragma unroll
                for (int s = 0; s < NW; ++s)
                    o += __uint_as_float(((unsigned)oSh[s][row][il*4 + c]) << 16);
                y[c] = o*di + ((const float*)&pr)[c];
            }
            float ssum = y[0] + y[1] + y[2] + y[3];
            #pragma unroll
            for (int off = 16; off >= 1; off >>= 1) ssum += __shfl_xor(ssum, off);
            float mu = ssum * (1.f/128.f);
            float vs = 0.f;
            #pragma unroll
            for (int c = 0; c < 4; ++c) { float d = y[c] - mu; vs += d*d; }
            #pragma unroll
            for (int off = 16; off >= 1; off >>= 1) vs += __shfl_xor(vs, off);
            float rs = rsqrtf(vs * (1.f/128.f) + 1e-3f);
            float4 g4 = *(const float4*)(lng + il*4);
            float4 b4 = *(const float4*)(lnb + il*4);
            float4 o4;
            #pragma unroll
            for (int c = 0; c < 4; ++c) {
                float o = (y[c] - mu)*rs*((const float*)&g4)[c] + ((const float*)&b4)[c];
                if (!(o == o)) o = 12345.0f;  // NaN sentinel (never hit on a passing run)
                ((float*)&o4)[c] = o;
            }
            *(float4*)(fout + base) = o4;
        }
    }
}

extern "C" void kernel_launch(void* const* d_in, const int* in_sizes, int n_in,
                              void* d_out, int out_size, void* d_ws, size_t ws_size,
                              hipStream_t stream)
{
    const float* x   = (const float*)d_in[0];
    // d_in[1] = emb is dead: adj = sigmoid(l2norm(emb)@l2norm(emb)^T) in [0.27,1],
    // diag forced 1 -> adj==0 never true -> dense attention.
    const float* q1w = (const float*)d_in[2];
    const float* q1b = (const float*)d_in[3];
    const float* k1w = (const float*)d_in[4];
    const float* k1b = (const float*)d_in[5];
    const float* v1w = (const float*)d_in[6];
    const float* v1b = (const float*)d_in[7];
    const float* q2w = (const float*)d_in[8];
    const float* q2b = (const float*)d_in[9];
    const float* k2w = (const float*)d_in[10];
    const float* k2b = (const float*)d_in[11];
    const float* v2w = (const float*)d_in[12];
    const float* v2b = (const float*)d_in[13];
    const float* pw  = (const float*)d_in[14];
    const float* lng = (const float*)d_in[15];
    const float* lnb = (const float*)d_in[16];

    // Workspace: 12 MB (proven). q/k/vT slots reused across the two layers.
    const size_t SZ = (size_t)NB*NN*DOUT;           // 1,048,576 elements
    char* wsb = (char*)d_ws;
    bf16*  qA   = (bf16*)(wsb + 0*SZ*2);            // 2 MB
    bf16*  kA   = (bf16*)(wsb + 1*SZ*2);            // 2 MB
    bf16*  vT   = (bf16*)(wsb + 2*SZ*2);            // 2 MB  [b][key/64][128][64]
    float* proj = (float*)(wsb + 3*SZ*2);           // 4 MB
    bf16*  h    = (bf16*)(wsb + 3*SZ*2 + SZ*4);     // 2 MB

    k_gemm1<<<dim3(128, 8), 256, 0, stream>>>(x, q1w, q1b, k1w, k1b, v1w, v1b, pw,
                                              qA, kA, vT, proj);
    // NQ=2: 1024 blocks (64 q-blocks x 16 bh)
    k_attn_mfma<32, 0, 4, 2><<<dim3(64, 16), 256, 0, stream>>>(
        qA, kA, vT, nullptr, nullptr, nullptr, h, nullptr);
    k_gemm2<<<dim3(128, 6), 256, 0, stream>>>(h, q2w, q2b, k2w, k2b, v2w, v2b,
                                              qA, kA, vT);
    // NQ=2: 256 blocks (64 q-blocks x 4 b)
    k_attn_mfma<128, 1, 8, 2><<<dim3(64, 4), 512, 0, stream>>>(
        qA, kA, vT, proj, lng, lnb, nullptr, (float*)d_out);
}